// Round 8
// baseline (279.608 us; speedup 1.0000x reference)
//
#include <hip/hip_runtime.h>
#include <hip/hip_bf16.h>
#include <cstdio>

#define B_  64
#define I_  2048
#define J_  16
#define N_  64
#define D_  16
#define K_  1024     // N_*D_
#define KTOT 32768   // I_*J_ : flattened K for the s0 GEMM

typedef __attribute__((ext_vector_type(8))) unsigned short ushort8_t;
using short8 = __attribute__((ext_vector_type(8))) short;
using f32x4  = __attribute__((ext_vector_type(4))) float;

__device__ __forceinline__ float bf2f(unsigned short h) {
  return __uint_as_float(((unsigned int)h) << 16);
}

// ---------- x fp32 -> bf16 (A matrix of the s0 GEMM), [b][(i,j)] flat ----------
__global__ __launch_bounds__(256) void conv_x_k(const float* __restrict__ x,
                                                unsigned short* __restrict__ xb) {
  const int idx = blockIdx.x * 256 + threadIdx.x;   // 131072 threads
  const float4* xp = (const float4*)x;
  uint2* op = (uint2*)xb;
#pragma unroll
  for (int r = 0; r < 4; ++r) {
    float4 v = xp[idx + r * 131072];
    __hip_bfloat162 p0 = __float22bfloat162_rn(float2{v.x, v.y});
    __hip_bfloat162 p1 = __float22bfloat162_rn(float2{v.z, v.w});
    uint2 o; o.x = *(unsigned int*)&p0; o.y = *(unsigned int*)&p1;
    op[idx + r * 131072] = o;
  }
}

// ---------- s0 = (1/64) * x[64 x 32768] * W[32768 x 1024], bf16 MFMA ----------
// grid (64 n-tiles, 8 k-splits), 256 threads (4 waves = 4 M-tiles of 16 b).
// W staged fp32->bf16 into LDS [n][k] with XOR swizzle (conflict-free b128 reads).
#define KC 4096
#define KS 512
__global__ __launch_bounds__(256) void s0_gemm_k(const unsigned short* __restrict__ xb,
                                                 const float* __restrict__ W,
                                                 float* __restrict__ s0) {
  const int t = threadIdx.x;
  const int w = t >> 6, l = t & 63;
  const int n0 = blockIdx.x * 16;
  const int k0 = blockIdx.y * KC;
  const int m0 = w * 16;

  __shared__ unsigned short Bl[2][16 * KS];   // 2 x 16 KB

  auto stage = [&](int c, int buf) {
    const int kl0 = (t >> 2);        // 0..63
    const int n4  = (t & 3) * 4;     // 0,4,8,12
#pragma unroll
    for (int r = 0; r < 8; ++r) {
      int kl = kl0 + r * 64;         // 0..511
      float4 wv = *(const float4*)&W[(size_t)(k0 + c * KS + kl) * K_ + n0 + n4];
      __hip_bfloat162 q0 = __float22bfloat162_rn(float2{wv.x, wv.y});
      __hip_bfloat162 q1 = __float22bfloat162_rn(float2{wv.z, wv.w});
      unsigned int u01 = *(unsigned int*)&q0;
      unsigned int u23 = *(unsigned int*)&q1;
      unsigned short hs[4] = {(unsigned short)u01, (unsigned short)(u01 >> 16),
                              (unsigned short)u23, (unsigned short)(u23 >> 16)};
#pragma unroll
      for (int e = 0; e < 4; ++e) {
        int n = n4 + e;
        unsigned off = (unsigned)(n * (KS * 2) + kl * 2) ^ ((unsigned)(n & 7) << 4);
        *(unsigned short*)((char*)&Bl[buf][0] + off) = hs[e];
      }
    }
  };

  f32x4 acc = {0.f, 0.f, 0.f, 0.f};
  const unsigned short* arow = xb + (size_t)(m0 + (l & 15)) * KTOT + k0 + ((l >> 4) * 8);
  const unsigned baseoff = (unsigned)((l & 15) * (KS * 2)) ;
  const unsigned kfrag   = (unsigned)((l >> 4) * 8);

  stage(0, 0);
  __syncthreads();
  for (int c = 0; c < KC / KS; ++c) {
    int buf = c & 1;
    if (c + 1 < KC / KS) stage(c + 1, buf ^ 1);
#pragma unroll
    for (int ks = 0; ks < KS; ks += 32) {
      short8 a = *(const short8*)(arow + c * KS + ks);
      unsigned boff = (baseoff + (ks + kfrag) * 2) ^ ((unsigned)(l & 7) << 4);
      short8 b = *(const short8*)((const char*)&Bl[buf][0] + boff);
      acc = __builtin_amdgcn_mfma_f32_16x16x32_bf16(a, b, acc, 0, 0, 0);
    }
    __syncthreads();
  }

  const int col = l & 15, rq = (l >> 4) * 4;   // C: col=lane&15, row=(lane>>4)*4+reg
#pragma unroll
  for (int r = 0; r < 4; ++r)
    atomicAdd(&s0[(size_t)(m0 + rq + r) * K_ + n0 + col], acc[r] * (1.0f / 64.0f));
}

// ---------- projection: u_hat[b][i][k] bf16 (round-3 structure + cvt_pk) ----------
__global__ __launch_bounds__(256) void project_k(const float* __restrict__ x,
                                                 const float* __restrict__ W,
                                                 unsigned short* __restrict__ uh) {
  const int i  = blockIdx.x >> 1;
  const int b0 = (blockIdx.x & 1) * 32;
  const int t  = threadIdx.x;

  __shared__ float4 xl[32 * 4];        // 2 KB
  if (t < 128) {
    int bb = t >> 2, q = t & 3;
    xl[t] = ((const float4*)(x + ((size_t)(b0 + bb) * I_ + i) * J_))[q];
  }

  const float4* Wp = (const float4*)(W + (size_t)i * (J_ * K_));
  float4 w[J_];
#pragma unroll
  for (int j = 0; j < J_; ++j) w[j] = Wp[j * (K_ / 4) + t];

  __syncthreads();

  unsigned short* op = uh + ((size_t)b0 * I_ + i) * K_ + t * 4;

  float4 xa0 = xl[0], xa1 = xl[1], xa2 = xl[2], xa3 = xl[3];
  for (int bb = 0; bb < 32; ++bb) {
    float4 xb0, xb1, xb2, xb3;
    if (bb < 31) {
      xb0 = xl[(bb + 1) * 4 + 0]; xb1 = xl[(bb + 1) * 4 + 1];
      xb2 = xl[(bb + 1) * 4 + 2]; xb3 = xl[(bb + 1) * 4 + 3];
    }
    float4 acc = {0.f, 0.f, 0.f, 0.f};
#define FMA4(xc, j0)  \
    acc.x += xc.x * w[j0].x;     acc.y += xc.x * w[j0].y;     acc.z += xc.x * w[j0].z;     acc.w += xc.x * w[j0].w; \
    acc.x += xc.y * w[j0+1].x;   acc.y += xc.y * w[j0+1].y;   acc.z += xc.y * w[j0+1].z;   acc.w += xc.y * w[j0+1].w; \
    acc.x += xc.z * w[j0+2].x;   acc.y += xc.z * w[j0+2].y;   acc.z += xc.z * w[j0+2].z;   acc.w += xc.z * w[j0+2].w; \
    acc.x += xc.w * w[j0+3].x;   acc.y += xc.w * w[j0+3].y;   acc.z += xc.w * w[j0+3].z;   acc.w += xc.w * w[j0+3].w;
    FMA4(xa0, 0) FMA4(xa1, 4) FMA4(xa2, 8) FMA4(xa3, 12)
#undef FMA4
    __hip_bfloat162 p0 = __float22bfloat162_rn(float2{acc.x, acc.y});
    __hip_bfloat162 p1 = __float22bfloat162_rn(float2{acc.z, acc.w});
    uint2 st;
    st.x = *(unsigned int*)&p0;
    st.y = *(unsigned int*)&p1;
    *(uint2*)op = st;
    op += (size_t)I_ * K_;
    xa0 = xb0; xa1 = xb1; xa2 = xb2; xa3 = xb3;
  }
}

// ---------- routing passes (unchanged round-3 logic, [b][i][k]) ----------
// MODE 1: logit = dot(u, v0),           v0 = squash(s0 + bias)
// MODE 2: logit = dot(u, v0)+dot(u,v1)  (b-logits recomputed, never materialized)
template <int MODE>
__global__ __launch_bounds__(256, 4) void route_k(const unsigned short* __restrict__ uh,
                                                  const float* __restrict__ sa,
                                                  const float* __restrict__ sb,
                                                  const float* __restrict__ bias,
                                                  float* __restrict__ s_out) {
  const int t    = threadIdx.x;
  const int lane = t & 63;            // = n
  const int wv   = t >> 6;            // 0..3
  const int b    = blockIdx.x >> 4;
  const int iw   = ((blockIdx.x & 15) << 2) + wv;
  const int i0   = iw * 32;

  float va_r[16], vb_r[16];
  {
    float bs[16];
#pragma unroll
    for (int q = 0; q < 4; ++q) {
      float4 bb4 = *(const float4*)&bias[lane * 16 + q * 4];
      bs[q*4+0] = bb4.x; bs[q*4+1] = bb4.y; bs[q*4+2] = bb4.z; bs[q*4+3] = bb4.w;
    }
    {
      float nn = 0.f;
#pragma unroll
      for (int q = 0; q < 4; ++q) {
        float4 tmp = *(const float4*)&sa[(size_t)b * K_ + lane * 16 + q * 4];
        va_r[q*4+0] = tmp.x + bs[q*4+0]; va_r[q*4+1] = tmp.y + bs[q*4+1];
        va_r[q*4+2] = tmp.z + bs[q*4+2]; va_r[q*4+3] = tmp.w + bs[q*4+3];
      }
#pragma unroll
      for (int d = 0; d < 16; ++d) nn += va_r[d] * va_r[d];
      float n2 = nn + 1e-7f;
      float f = sqrtf(n2) / (1.0f + n2);
#pragma unroll
      for (int d = 0; d < 16; ++d) va_r[d] *= f;
    }
    if (MODE == 2) {
      float nn = 0.f;
#pragma unroll
      for (int q = 0; q < 4; ++q) {
        float4 tmp = *(const float4*)&sb[(size_t)b * K_ + lane * 16 + q * 4];
        vb_r[q*4+0] = tmp.x + bs[q*4+0]; vb_r[q*4+1] = tmp.y + bs[q*4+1];
        vb_r[q*4+2] = tmp.z + bs[q*4+2]; vb_r[q*4+3] = tmp.w + bs[q*4+3];
      }
#pragma unroll
      for (int d = 0; d < 16; ++d) nn += vb_r[d] * vb_r[d];
      float n2 = nn + 1e-7f;
      float f = sqrtf(n2) / (1.0f + n2);
#pragma unroll
      for (int d = 0; d < 16; ++d) vb_r[d] *= f;
    }
  }

  constexpr int IPW = 32;
  constexpr int PF  = (MODE == 2) ? 2 : 4;

  const unsigned short* base = uh + (size_t)b * I_ * K_ + lane * 16;

  struct Row { ushort8_t lo, hi; };
  Row buf[PF];
#pragma unroll
  for (int p = 0; p < PF; ++p) {
    int ip = (i0 + p) & (I_ - 1);
    buf[p].lo = *(const ushort8_t*)(base + (size_t)ip * K_);
    buf[p].hi = *(const ushort8_t*)(base + (size_t)ip * K_ + 8);
  }

  float s_loc[16];
#pragma unroll
  for (int d = 0; d < 16; ++d) s_loc[d] = 0.f;

  for (int ii = 0; ii < IPW; ii += PF) {
#pragma unroll
    for (int p = 0; p < PF; ++p) {
      float u[16];
#pragma unroll
      for (int e = 0; e < 8; ++e) u[e]     = bf2f(buf[p].lo[e]);
#pragma unroll
      for (int e = 0; e < 8; ++e) u[8 + e] = bf2f(buf[p].hi[e]);

      int ip = (i0 + ii + p + PF) & (I_ - 1);
      buf[p].lo = *(const ushort8_t*)(base + (size_t)ip * K_);
      buf[p].hi = *(const ushort8_t*)(base + (size_t)ip * K_ + 8);

      float bl = 0.f;
#pragma unroll
      for (int d = 0; d < 16; ++d) bl += u[d] * va_r[d];
      if (MODE == 2) {
        float b2 = 0.f;
#pragma unroll
        for (int d = 0; d < 16; ++d) b2 += u[d] * vb_r[d];
        bl += b2;
      }
      float m = bl;
      m = fmaxf(m, __shfl_xor(m, 1));
      m = fmaxf(m, __shfl_xor(m, 2));
      m = fmaxf(m, __shfl_xor(m, 4));
      m = fmaxf(m, __shfl_xor(m, 8));
      m = fmaxf(m, __shfl_xor(m, 16));
      m = fmaxf(m, __shfl_xor(m, 32));
      float e = __expf(bl - m);
      float ss = e;
      ss += __shfl_xor(ss, 1);
      ss += __shfl_xor(ss, 2);
      ss += __shfl_xor(ss, 4);
      ss += __shfl_xor(ss, 8);
      ss += __shfl_xor(ss, 16);
      ss += __shfl_xor(ss, 32);
      float c = __fdividef(e, ss);
#pragma unroll
      for (int d = 0; d < 16; ++d) s_loc[d] += c * u[d];
    }
  }

  __shared__ float sred[4][64 * 17];
#pragma unroll
  for (int d = 0; d < 16; ++d) sred[wv][lane * 17 + d] = s_loc[d];
  __syncthreads();
#pragma unroll
  for (int e = 0; e < 4; ++e) {
    int idx = t * 4 + e;
    int n = idx >> 4, d = idx & 15;
    float val = sred[0][n*17+d] + sred[1][n*17+d] + sred[2][n*17+d] + sred[3][n*17+d];
    atomicAdd(&s_out[(size_t)b * K_ + idx], val);
  }
}

// ---------- final squash ----------
__global__ __launch_bounds__(256) void squash_k(const float* __restrict__ s_in,
                                                const float* __restrict__ bias,
                                                float* __restrict__ v_out) {
  const int b = blockIdx.x, t = threadIdx.x, k0 = t * 4;
  float4 s = *(const float4*)&s_in[b * K_ + k0];
  float4 bb = *(const float4*)&bias[k0];
  s.x += bb.x; s.y += bb.y; s.z += bb.z; s.w += bb.w;
  float p = s.x * s.x + s.y * s.y + s.z * s.z + s.w * s.w;
  p += __shfl_xor(p, 1);
  p += __shfl_xor(p, 2);
  float n2 = p + 1e-7f;
  float nrm = sqrtf(n2);
  float f = nrm / (1.0f + n2);
  float4 o = {s.x * f, s.y * f, s.z * f, s.w * f};
  *(float4*)&v_out[b * K_ + k0] = o;
}

extern "C" void kernel_launch(void* const* d_in, const int* in_sizes, int n_in,
                              void* d_out, int out_size, void* d_ws, size_t ws_size,
                              hipStream_t stream) {
  const float* x    = (const float*)d_in[0];
  const float* W    = (const float*)d_in[1];
  const float* bias = (const float*)d_in[2];
  float* out = (float*)d_out;

  char* ws = (char*)d_ws;
  size_t off = 0;
  unsigned short* uh = (unsigned short*)(ws + off); off += (size_t)B_ * I_ * K_ * 2; // 268 MB
  float* s0 = (float*)(ws + off); off += (size_t)B_ * K_ * 4;
  float* s1 = (float*)(ws + off); off += (size_t)B_ * K_ * 4;
  float* s2 = (float*)(ws + off); off += (size_t)B_ * K_ * 4;
  unsigned short* xbf = (unsigned short*)(ws + off); off += (size_t)B_ * KTOT * 2;   // 4 MB

  if (ws_size < off)
    fprintf(stderr, "ClassCapsule: ws_size=%zu < needed=%zu — expect corruption\n", ws_size, off);

  (void)hipMemsetAsync(s0, 0, (size_t)3 * B_ * K_ * 4, stream);  // s0,s1,s2 contiguous

  conv_x_k<<<dim3(512), dim3(256), 0, stream>>>(x, xbf);
  s0_gemm_k<<<dim3(64, 8), dim3(256), 0, stream>>>(xbf, W, s0);   // replaces route<0>; warms W in L3
  project_k<<<dim3(I_ * 2), dim3(256), 0, stream>>>(x, W, uh);

  route_k<1><<<dim3(1024), dim3(256), 0, stream>>>(uh, s0, nullptr, bias, s1);
  route_k<2><<<dim3(1024), dim3(256), 0, stream>>>(uh, s0, s1, bias, s2);
  squash_k<<<dim3(B_), dim3(256), 0, stream>>>(s2, bias, out);
}

// Round 11
// 227.019 us; speedup vs baseline: 1.2317x; 1.2317x over previous
//
#include <hip/hip_runtime.h>
#include <hip/hip_bf16.h>
#include <hip/hip_fp16.h>
#include <cstdio>

#define B_  64
#define I_  2048
#define J_  16
#define N_  64
#define D_  16
#define K_  1024   // N_*D_

// ---------- projection: u_hat int8 [b][i][k] + per-(b,i,n) f16 scale ----------
// Block = (i, half of b), grid 4096 (proven 85.6us structure). W[i] k-slice in
// regs; x rows in LDS. Quantize: absmax over the 16 elems of n via 2-step
// __shfl_xor across the 4-lane group; q = rint(u*127/amax); store 4B/thread/b.
__global__ __launch_bounds__(256) void project_k(const float* __restrict__ x,
                                                 const float* __restrict__ W,
                                                 unsigned char* __restrict__ uh,
                                                 unsigned short* __restrict__ sc) {
  const int i  = blockIdx.x >> 1;
  const int b0 = (blockIdx.x & 1) * 32;
  const int t  = threadIdx.x;

  __shared__ float4 xl[32 * 4];        // 2 KB
  if (t < 128) {
    int bb = t >> 2, q = t & 3;
    xl[t] = ((const float4*)(x + ((size_t)(b0 + bb) * I_ + i) * J_))[q];
  }

  const float4* Wp = (const float4*)(W + (size_t)i * (J_ * K_));
  float4 w[J_];
#pragma unroll
  for (int j = 0; j < J_; ++j) w[j] = Wp[j * (K_ / 4) + t];

  __syncthreads();

  unsigned char* op = uh + ((size_t)b0 * I_ + i) * K_ + t * 4;
  unsigned short* scp = sc + ((size_t)b0 * I_ + i) * N_ + (t >> 2);
  const bool lead = (t & 3) == 0;

  float4 xa0 = xl[0], xa1 = xl[1], xa2 = xl[2], xa3 = xl[3];
  for (int bb = 0; bb < 32; ++bb) {
    float4 xb0, xb1, xb2, xb3;
    if (bb < 31) {
      xb0 = xl[(bb + 1) * 4 + 0]; xb1 = xl[(bb + 1) * 4 + 1];
      xb2 = xl[(bb + 1) * 4 + 2]; xb3 = xl[(bb + 1) * 4 + 3];
    }
    float4 acc = {0.f, 0.f, 0.f, 0.f};
#define FMA4(xc, j0)  \
    acc.x += xc.x * w[j0].x;     acc.y += xc.x * w[j0].y;     acc.z += xc.x * w[j0].z;     acc.w += xc.x * w[j0].w; \
    acc.x += xc.y * w[j0+1].x;   acc.y += xc.y * w[j0+1].y;   acc.z += xc.y * w[j0+1].z;   acc.w += xc.y * w[j0+1].w; \
    acc.x += xc.z * w[j0+2].x;   acc.y += xc.z * w[j0+2].y;   acc.z += xc.z * w[j0+2].z;   acc.w += xc.z * w[j0+2].w; \
    acc.x += xc.w * w[j0+3].x;   acc.y += xc.w * w[j0+3].y;   acc.z += xc.w * w[j0+3].z;   acc.w += xc.w * w[j0+3].w;
    FMA4(xa0, 0) FMA4(xa1, 4) FMA4(xa2, 8) FMA4(xa3, 12)
#undef FMA4
    // per-n absmax (16 elems = 4 lanes x 4)
    float ax = fmaxf(fmaxf(fabsf(acc.x), fabsf(acc.y)), fmaxf(fabsf(acc.z), fabsf(acc.w)));
    ax = fmaxf(ax, __shfl_xor(ax, 1));
    ax = fmaxf(ax, __shfl_xor(ax, 2));
    float inv = ax > 0.f ? __fdividef(127.0f, ax) : 0.f;
    int q0 = (int)rintf(acc.x * inv);
    int q1 = (int)rintf(acc.y * inv);
    int q2 = (int)rintf(acc.z * inv);
    int q3 = (int)rintf(acc.w * inv);
    unsigned st = (unsigned)(q0 & 255) | ((unsigned)(q1 & 255) << 8)
                | ((unsigned)(q2 & 255) << 16) | ((unsigned)(q3 & 255) << 24);
    *(unsigned int*)op = st;                       // 4 B, wave-contiguous
    if (lead)
      *scp = __half_as_ushort(__float2half_rn(ax * (1.0f / 127.0f)));
    op  += (size_t)I_ * K_;
    scp += (size_t)I_ * N_;
    xa0 = xb0; xa1 = xb1; xa2 = xb2; xa3 = xb3;
  }
}

// ---------- routing on int8 u_hat: lane = n; row read = 16 B data + 2 B scale ----------
// MODE 0: c = 1/64 exactly -> s += scale*r, final *1/64.
// MODE 1: logit = scale * dot(r, v0),        v0 = squash(s0 + bias)
// MODE 2: logit = scale * dot(r, v0+v1)      (u.v0 + u.v1 = u.(v0+v1))
template <int MODE>
__global__ __launch_bounds__(256, 4) void route_k(const unsigned char* __restrict__ uh,
                                                  const unsigned short* __restrict__ sc,
                                                  const float* __restrict__ sa,
                                                  const float* __restrict__ sb,
                                                  const float* __restrict__ bias,
                                                  float* __restrict__ s_out) {
  const int t    = threadIdx.x;
  const int lane = t & 63;            // = n
  const int wv   = t >> 6;            // 0..3
  const int b    = blockIdx.x >> 4;
  const int iw   = ((blockIdx.x & 15) << 2) + wv;
  const int i0   = iw * 32;

  float vsum[16];
  if (MODE >= 1) {
    float bs[16];
#pragma unroll
    for (int q = 0; q < 4; ++q) {
      float4 bb4 = *(const float4*)&bias[lane * 16 + q * 4];
      bs[q*4+0] = bb4.x; bs[q*4+1] = bb4.y; bs[q*4+2] = bb4.z; bs[q*4+3] = bb4.w;
    }
    {
      float va[16], nn = 0.f;
#pragma unroll
      for (int q = 0; q < 4; ++q) {
        float4 tmp = *(const float4*)&sa[(size_t)b * K_ + lane * 16 + q * 4];
        va[q*4+0] = tmp.x + bs[q*4+0]; va[q*4+1] = tmp.y + bs[q*4+1];
        va[q*4+2] = tmp.z + bs[q*4+2]; va[q*4+3] = tmp.w + bs[q*4+3];
      }
#pragma unroll
      for (int d = 0; d < 16; ++d) nn += va[d] * va[d];
      float n2 = nn + 1e-7f;
      float f = sqrtf(n2) / (1.0f + n2);
#pragma unroll
      for (int d = 0; d < 16; ++d) vsum[d] = va[d] * f;
    }
    if (MODE == 2) {
      float vb[16], nn = 0.f;
#pragma unroll
      for (int q = 0; q < 4; ++q) {
        float4 tmp = *(const float4*)&sb[(size_t)b * K_ + lane * 16 + q * 4];
        vb[q*4+0] = tmp.x + bs[q*4+0]; vb[q*4+1] = tmp.y + bs[q*4+1];
        vb[q*4+2] = tmp.z + bs[q*4+2]; vb[q*4+3] = tmp.w + bs[q*4+3];
      }
#pragma unroll
      for (int d = 0; d < 16; ++d) nn += vb[d] * vb[d];
      float n2 = nn + 1e-7f;
      float f = sqrtf(n2) / (1.0f + n2);
#pragma unroll
      for (int d = 0; d < 16; ++d) vsum[d] += vb[d] * f;
    }
  }

  constexpr int IPW = 32;
  constexpr int PF  = 4;

  const unsigned char*  base = uh + (size_t)b * I_ * K_ + lane * 16;
  const unsigned short* scb  = sc + (size_t)b * I_ * N_ + lane;

  uint4 dbuf[PF];
  unsigned short hbuf[PF];
#pragma unroll
  for (int p = 0; p < PF; ++p) {
    int ip = (i0 + p) & (I_ - 1);
    dbuf[p] = *(const uint4*)(base + (size_t)ip * K_);
    hbuf[p] = scb[(size_t)ip * N_];
  }

  float s_loc[16];
#pragma unroll
  for (int d = 0; d < 16; ++d) s_loc[d] = 0.f;

  for (int ii = 0; ii < IPW; ii += PF) {
#pragma unroll
    for (int p = 0; p < PF; ++p) {
      float scale = __half2float(__ushort_as_half(hbuf[p]));
      float u[16];
      {
        unsigned wdr;
        wdr = dbuf[p].x;
        u[0]  = (float)((signed char)(wdr));       u[1]  = (float)((signed char)(wdr >> 8));
        u[2]  = (float)((signed char)(wdr >> 16)); u[3]  = (float)((signed char)(wdr >> 24));
        wdr = dbuf[p].y;
        u[4]  = (float)((signed char)(wdr));       u[5]  = (float)((signed char)(wdr >> 8));
        u[6]  = (float)((signed char)(wdr >> 16)); u[7]  = (float)((signed char)(wdr >> 24));
        wdr = dbuf[p].z;
        u[8]  = (float)((signed char)(wdr));       u[9]  = (float)((signed char)(wdr >> 8));
        u[10] = (float)((signed char)(wdr >> 16)); u[11] = (float)((signed char)(wdr >> 24));
        wdr = dbuf[p].w;
        u[12] = (float)((signed char)(wdr));       u[13] = (float)((signed char)(wdr >> 8));
        u[14] = (float)((signed char)(wdr >> 16)); u[15] = (float)((signed char)(wdr >> 24));
      }

      int ip = (i0 + ii + p + PF) & (I_ - 1);
      dbuf[p] = *(const uint4*)(base + (size_t)ip * K_);
      hbuf[p] = scb[(size_t)ip * N_];

      if (MODE == 0) {
#pragma unroll
        for (int d = 0; d < 16; ++d) s_loc[d] += scale * u[d];
      } else {
        float draw = 0.f;
#pragma unroll
        for (int d = 0; d < 16; ++d) draw += u[d] * vsum[d];
        float bl = draw * scale;
        float m = bl;
        m = fmaxf(m, __shfl_xor(m, 1));
        m = fmaxf(m, __shfl_xor(m, 2));
        m = fmaxf(m, __shfl_xor(m, 4));
        m = fmaxf(m, __shfl_xor(m, 8));
        m = fmaxf(m, __shfl_xor(m, 16));
        m = fmaxf(m, __shfl_xor(m, 32));
        float e = __expf(bl - m);
        float ss = e;
        ss += __shfl_xor(ss, 1);
        ss += __shfl_xor(ss, 2);
        ss += __shfl_xor(ss, 4);
        ss += __shfl_xor(ss, 8);
        ss += __shfl_xor(ss, 16);
        ss += __shfl_xor(ss, 32);
        float cs = __fdividef(e, ss) * scale;
#pragma unroll
        for (int d = 0; d < 16; ++d) s_loc[d] += cs * u[d];
      }
    }
  }

  if (MODE == 0) {
#pragma unroll
    for (int d = 0; d < 16; ++d) s_loc[d] *= (1.0f / 64.0f);
  }

  __shared__ float sred[4][64 * 17];
#pragma unroll
  for (int d = 0; d < 16; ++d) sred[wv][lane * 17 + d] = s_loc[d];
  __syncthreads();
#pragma unroll
  for (int e = 0; e < 4; ++e) {
    int idx = t * 4 + e;
    int n = idx >> 4, d = idx & 15;
    float val = sred[0][n*17+d] + sred[1][n*17+d] + sred[2][n*17+d] + sred[3][n*17+d];
    atomicAdd(&s_out[(size_t)b * K_ + idx], val);
  }
}

// ---------- final squash ----------
__global__ __launch_bounds__(256) void squash_k(const float* __restrict__ s_in,
                                                const float* __restrict__ bias,
                                                float* __restrict__ v_out) {
  const int b = blockIdx.x, t = threadIdx.x, k0 = t * 4;
  float4 s = *(const float4*)&s_in[b * K_ + k0];
  float4 bb = *(const float4*)&bias[k0];
  s.x += bb.x; s.y += bb.y; s.z += bb.z; s.w += bb.w;
  float p = s.x * s.x + s.y * s.y + s.z * s.z + s.w * s.w;
  p += __shfl_xor(p, 1);
  p += __shfl_xor(p, 2);
  float n2 = p + 1e-7f;
  float nrm = sqrtf(n2);
  float f = nrm / (1.0f + n2);
  float4 o = {s.x * f, s.y * f, s.z * f, s.w * f};
  *(float4*)&v_out[b * K_ + k0] = o;
}

extern "C" void kernel_launch(void* const* d_in, const int* in_sizes, int n_in,
                              void* d_out, int out_size, void* d_ws, size_t ws_size,
                              hipStream_t stream) {
  const float* x    = (const float*)d_in[0];
  const float* W    = (const float*)d_in[1];
  const float* bias = (const float*)d_in[2];
  float* out = (float*)d_out;

  char* ws = (char*)d_ws;
  size_t off = 0;
  unsigned char*  uh = (unsigned char*)(ws + off);  off += (size_t)B_ * I_ * K_;      // 134 MB int8
  unsigned short* sc = (unsigned short*)(ws + off); off += (size_t)B_ * I_ * N_ * 2;  // 16.8 MB f16 scales
  float* s0 = (float*)(ws + off); off += (size_t)B_ * K_ * 4;
  float* s1 = (float*)(ws + off); off += (size_t)B_ * K_ * 4;
  float* s2 = (float*)(ws + off); off += (size_t)B_ * K_ * 4;

  if (ws_size < off)
    fprintf(stderr, "ClassCapsule: ws_size=%zu < needed=%zu — expect corruption\n", ws_size, off);

  (void)hipMemsetAsync(s0, 0, (size_t)3 * B_ * K_ * 4, stream);  // s0,s1,s2 contiguous

  project_k<<<dim3(I_ * 2), dim3(256), 0, stream>>>(x, W, uh, sc);

  route_k<0><<<dim3(1024), dim3(256), 0, stream>>>(uh, sc, nullptr, nullptr, bias, s0);
  route_k<1><<<dim3(1024), dim3(256), 0, stream>>>(uh, sc, s0, nullptr, bias, s1);
  route_k<2><<<dim3(1024), dim3(256), 0, stream>>>(uh, sc, s0, s1, bias, s2);
  squash_k<<<dim3(B_), dim3(256), 0, stream>>>(s2, bias, out);
}

// Round 12
// 198.072 us; speedup vs baseline: 1.4116x; 1.1461x over previous
//
#include <hip/hip_runtime.h>
#include <hip/hip_fp16.h>
#include <cstdio>

#define B_  64
#define I_  2048
#define J_  16
#define N_  64
#define D_  16
#define K_  1024   // N_*D_

typedef __attribute__((ext_vector_type(2))) float float2v;

#if __has_builtin(__builtin_amdgcn_cvt_pk_u8_f32)
#define CVTPK_U8(f, sel, old) (unsigned)__builtin_amdgcn_cvt_pk_u8_f32((f), (sel), (old))
#else
__device__ __forceinline__ unsigned cvtpk_u8_sw(float f, unsigned sel, unsigned old) {
  unsigned b = (unsigned)(int)f & 0xffu;
  unsigned sh = sel * 8u;
  return (old & ~(0xffu << sh)) | (b << sh);
}
#define CVTPK_U8(f, sel, old) cvtpk_u8_sw((f), (sel), (old))
#endif

// packed f32 FMA with scalar broadcast from src0's lo/hi half (VOP3P op_sel)
__device__ __forceinline__ void pk_fma_lo(float2v& a, float2v x, float2v w) {
  asm("v_pk_fma_f32 %0, %1, %2, %0 op_sel:[0,0,0] op_sel_hi:[0,1,1]"
      : "+v"(a) : "v"(x), "v"(w));
}
__device__ __forceinline__ void pk_fma_hi(float2v& a, float2v x, float2v w) {
  asm("v_pk_fma_f32 %0, %1, %2, %0 op_sel:[1,0,0] op_sel_hi:[1,1,1]"
      : "+v"(a) : "v"(x), "v"(w));
}

// ---------- projection: u_hat u8(biased int8) [b][i][k] + per-(b,i,n) f16 scale ----
// Block = (i, half of b). W[i] k-slice TRULY in regs (launch_bounds relaxed);
// 32 v_pk_fma_f32 per b; quant via cvt_pk_u8; 4 B/lane contiguous stores.
__global__ __launch_bounds__(256, 3) void project_k(const float* __restrict__ x,
                                                    const float* __restrict__ W,
                                                    unsigned char* __restrict__ uh,
                                                    unsigned short* __restrict__ sc) {
  const int i  = blockIdx.x >> 1;
  const int b0 = (blockIdx.x & 1) * 32;
  const int t  = threadIdx.x;

  __shared__ float4 xl4[32 * 4];       // 2 KB: x[b0+bb][i][0..15]
  if (t < 128) {
    int bb = t >> 2, q = t & 3;
    xl4[t] = ((const float4*)(x + ((size_t)(b0 + bb) * I_ + i) * J_))[q];
  }

  const float4* Wp = (const float4*)(W + (size_t)i * (J_ * K_));
  float2v w2[32];                      // 64 VGPR: W[j][k0..k0+3] as 2 pairs per j
#pragma unroll
  for (int j = 0; j < J_; ++j) {
    float4 wv = Wp[j * (K_ / 4) + t];
    w2[2 * j]     = float2v{wv.x, wv.y};
    w2[2 * j + 1] = float2v{wv.z, wv.w};
  }
  __syncthreads();

  unsigned char*  op  = uh + ((size_t)b0 * I_ + i) * K_ + t * 4;
  unsigned short* scp = sc + ((size_t)b0 * I_ + i) * N_ + (t >> 2);
  const bool lead = (t & 3) == 0;
  const float2v* xlp = (const float2v*)xl4;   // 8 j-pairs per b

#define QUANT_STORE(A01, A23) do {                                              \
    float ax_ = fmaxf(fmaxf(fabsf((A01).x), fabsf((A01).y)),                    \
                      fmaxf(fabsf((A23).x), fabsf((A23).y)));                   \
    ax_ = fmaxf(ax_, __shfl_xor(ax_, 1));                                       \
    ax_ = fmaxf(ax_, __shfl_xor(ax_, 2));                                       \
    float inv_ = __fdividef(127.0f, fmaxf(ax_, 1e-30f));                        \
    float e0_ = rintf(fmaf((A01).x, inv_, 128.f));                              \
    float e1_ = rintf(fmaf((A01).y, inv_, 128.f));                              \
    float e2_ = rintf(fmaf((A23).x, inv_, 128.f));                              \
    float e3_ = rintf(fmaf((A23).y, inv_, 128.f));                              \
    unsigned pk_ = CVTPK_U8(e0_, 0u, 0u);                                       \
    pk_ = CVTPK_U8(e1_, 1u, pk_);                                               \
    pk_ = CVTPK_U8(e2_, 2u, pk_);                                               \
    pk_ = CVTPK_U8(e3_, 3u, pk_);                                               \
    *(unsigned int*)op = pk_;                                                   \
    if (lead) *scp = __half_as_ushort(__float2half_rn(ax_ * (1.0f / 127.0f))); \
    op  += (size_t)I_ * K_;                                                     \
    scp += (size_t)I_ * N_;                                                     \
  } while (0)

#define FMA_BODY(XP)                                                            \
    float2v a01 = {0.f, 0.f}, a23 = {0.f, 0.f};                                 \
    _Pragma("unroll")                                                           \
    for (int p = 0; p < 8; ++p) {                                               \
      pk_fma_lo(a01, (XP)[p], w2[4 * p + 0]);                                   \
      pk_fma_lo(a23, (XP)[p], w2[4 * p + 1]);                                   \
      pk_fma_hi(a01, (XP)[p], w2[4 * p + 2]);                                   \
      pk_fma_hi(a23, (XP)[p], w2[4 * p + 3]);                                   \
    }

  float2v xa[8], xb[8];
#pragma unroll
  for (int p = 0; p < 8; ++p) xa[p] = xlp[p];

  for (int bb = 0; bb < 32; bb += 2) {
#pragma unroll
    for (int p = 0; p < 8; ++p) xb[p] = xlp[(bb + 1) * 8 + p];
    {
      FMA_BODY(xa)
      QUANT_STORE(a01, a23);
    }
    if (bb + 2 < 32) {
#pragma unroll
      for (int p = 0; p < 8; ++p) xa[p] = xlp[(bb + 2) * 8 + p];
    }
    {
      FMA_BODY(xb)
      QUANT_STORE(a01, a23);
    }
  }
#undef FMA_BODY
#undef QUANT_STORE
}

// ---------- routing on u8 u_hat (e = q+128): lane = n; 16 B data + 2 B scale ----------
// u = scale*(e-128); bias folded: dots use (dot_e - 128*sum(v)); s-accum tracks csum.
// MODE 0: c = 1/64 exactly. MODE 1: logit = u.v0. MODE 2: logit = u.(v0+v1).
template <int MODE>
__global__ __launch_bounds__(256, 4) void route_k(const unsigned char* __restrict__ uh,
                                                  const unsigned short* __restrict__ sc,
                                                  const float* __restrict__ sa,
                                                  const float* __restrict__ sb,
                                                  const float* __restrict__ bias,
                                                  float* __restrict__ s_out) {
  const int t    = threadIdx.x;
  const int lane = t & 63;            // = n
  const int wv   = t >> 6;            // 0..3
  const int b    = blockIdx.x >> 4;
  const int iw   = ((blockIdx.x & 15) << 2) + wv;
  const int i0   = iw * 32;

  float vsum[16];
  float voff = 0.f;
  if (MODE >= 1) {
    float bs[16];
#pragma unroll
    for (int q = 0; q < 4; ++q) {
      float4 bb4 = *(const float4*)&bias[lane * 16 + q * 4];
      bs[q*4+0] = bb4.x; bs[q*4+1] = bb4.y; bs[q*4+2] = bb4.z; bs[q*4+3] = bb4.w;
    }
    {
      float va[16], nn = 0.f;
#pragma unroll
      for (int q = 0; q < 4; ++q) {
        float4 tmp = *(const float4*)&sa[(size_t)b * K_ + lane * 16 + q * 4];
        va[q*4+0] = tmp.x + bs[q*4+0]; va[q*4+1] = tmp.y + bs[q*4+1];
        va[q*4+2] = tmp.z + bs[q*4+2]; va[q*4+3] = tmp.w + bs[q*4+3];
      }
#pragma unroll
      for (int d = 0; d < 16; ++d) nn += va[d] * va[d];
      float n2 = nn + 1e-7f;
      float f = sqrtf(n2) / (1.0f + n2);
#pragma unroll
      for (int d = 0; d < 16; ++d) vsum[d] = va[d] * f;
    }
    if (MODE == 2) {
      float vb[16], nn = 0.f;
#pragma unroll
      for (int q = 0; q < 4; ++q) {
        float4 tmp = *(const float4*)&sb[(size_t)b * K_ + lane * 16 + q * 4];
        vb[q*4+0] = tmp.x + bs[q*4+0]; vb[q*4+1] = tmp.y + bs[q*4+1];
        vb[q*4+2] = tmp.z + bs[q*4+2]; vb[q*4+3] = tmp.w + bs[q*4+3];
      }
#pragma unroll
      for (int d = 0; d < 16; ++d) nn += vb[d] * vb[d];
      float n2 = nn + 1e-7f;
      float f = sqrtf(n2) / (1.0f + n2);
#pragma unroll
      for (int d = 0; d < 16; ++d) vsum[d] += vb[d] * f;
    }
    float tv = 0.f;
#pragma unroll
    for (int d = 0; d < 16; ++d) tv += vsum[d];
    voff = 128.0f * tv;
  }

  constexpr int IPW = 32;
  constexpr int PF  = 4;

  const unsigned char*  base = uh + (size_t)b * I_ * K_ + lane * 16;
  const unsigned short* scb  = sc + (size_t)b * I_ * N_ + lane;

  uint4 dbuf[PF];
  unsigned short hbuf[PF];
#pragma unroll
  for (int p = 0; p < PF; ++p) {
    int ip = (i0 + p) & (I_ - 1);
    dbuf[p] = *(const uint4*)(base + (size_t)ip * K_);
    hbuf[p] = scb[(size_t)ip * N_];
  }

  float s_loc[16];
#pragma unroll
  for (int d = 0; d < 16; ++d) s_loc[d] = 0.f;
  float csum = 0.f;

  for (int ii = 0; ii < IPW; ii += PF) {
#pragma unroll
    for (int p = 0; p < PF; ++p) {
      float scale = __half2float(__ushort_as_half(hbuf[p]));
      float u[16];
      {
        unsigned wd;
        wd = dbuf[p].x;   // (float)(byte) -> v_cvt_f32_ubyteN
        u[0]  = (float)(wd & 0xffu);         u[1]  = (float)((wd >> 8) & 0xffu);
        u[2]  = (float)((wd >> 16) & 0xffu); u[3]  = (float)(wd >> 24);
        wd = dbuf[p].y;
        u[4]  = (float)(wd & 0xffu);         u[5]  = (float)((wd >> 8) & 0xffu);
        u[6]  = (float)((wd >> 16) & 0xffu); u[7]  = (float)(wd >> 24);
        wd = dbuf[p].z;
        u[8]  = (float)(wd & 0xffu);         u[9]  = (float)((wd >> 8) & 0xffu);
        u[10] = (float)((wd >> 16) & 0xffu); u[11] = (float)(wd >> 24);
        wd = dbuf[p].w;
        u[12] = (float)(wd & 0xffu);         u[13] = (float)((wd >> 8) & 0xffu);
        u[14] = (float)((wd >> 16) & 0xffu); u[15] = (float)(wd >> 24);
      }

      int ip = (i0 + ii + p + PF) & (I_ - 1);
      dbuf[p] = *(const uint4*)(base + (size_t)ip * K_);
      hbuf[p] = scb[(size_t)ip * N_];

      if (MODE == 0) {
#pragma unroll
        for (int d = 0; d < 16; ++d) s_loc[d] = fmaf(scale, u[d], s_loc[d]);
        csum += scale;
      } else {
        float dot = 0.f;
#pragma unroll
        for (int d = 0; d < 16; ++d) dot = fmaf(u[d], vsum[d], dot);
        float bl = scale * (dot - voff);
        float m = bl;
        m = fmaxf(m, __shfl_xor(m, 1));
        m = fmaxf(m, __shfl_xor(m, 2));
        m = fmaxf(m, __shfl_xor(m, 4));
        m = fmaxf(m, __shfl_xor(m, 8));
        m = fmaxf(m, __shfl_xor(m, 16));
        m = fmaxf(m, __shfl_xor(m, 32));
        float e = __expf(bl - m);
        float ss = e;
        ss += __shfl_xor(ss, 1);
        ss += __shfl_xor(ss, 2);
        ss += __shfl_xor(ss, 4);
        ss += __shfl_xor(ss, 8);
        ss += __shfl_xor(ss, 16);
        ss += __shfl_xor(ss, 32);
        float cs = __fdividef(e, ss) * scale;
#pragma unroll
        for (int d = 0; d < 16; ++d) s_loc[d] = fmaf(cs, u[d], s_loc[d]);
        csum += cs;
      }
    }
  }

  // undo the +128 bias: sum(coeff*scale*(e-128)) = sum(coeff*scale*e) - 128*sum(coeff*scale)
#pragma unroll
  for (int d = 0; d < 16; ++d) s_loc[d] -= 128.0f * csum;
  if (MODE == 0) {
#pragma unroll
    for (int d = 0; d < 16; ++d) s_loc[d] *= (1.0f / 64.0f);
  }

  __shared__ float sred[4][64 * 17];
#pragma unroll
  for (int d = 0; d < 16; ++d) sred[wv][lane * 17 + d] = s_loc[d];
  __syncthreads();
#pragma unroll
  for (int e = 0; e < 4; ++e) {
    int idx = t * 4 + e;
    int n = idx >> 4, d = idx & 15;
    float val = sred[0][n*17+d] + sred[1][n*17+d] + sred[2][n*17+d] + sred[3][n*17+d];
    atomicAdd(&s_out[(size_t)b * K_ + idx], val);
  }
}

// ---------- final squash ----------
__global__ __launch_bounds__(256) void squash_k(const float* __restrict__ s_in,
                                                const float* __restrict__ bias,
                                                float* __restrict__ v_out) {
  const int b = blockIdx.x, t = threadIdx.x, k0 = t * 4;
  float4 s = *(const float4*)&s_in[b * K_ + k0];
  float4 bb = *(const float4*)&bias[k0];
  s.x += bb.x; s.y += bb.y; s.z += bb.z; s.w += bb.w;
  float p = s.x * s.x + s.y * s.y + s.z * s.z + s.w * s.w;
  p += __shfl_xor(p, 1);
  p += __shfl_xor(p, 2);
  float n2 = p + 1e-7f;
  float nrm = sqrtf(n2);
  float f = nrm / (1.0f + n2);
  float4 o = {s.x * f, s.y * f, s.z * f, s.w * f};
  *(float4*)&v_out[b * K_ + k0] = o;
}

extern "C" void kernel_launch(void* const* d_in, const int* in_sizes, int n_in,
                              void* d_out, int out_size, void* d_ws, size_t ws_size,
                              hipStream_t stream) {
  const float* x    = (const float*)d_in[0];
  const float* W    = (const float*)d_in[1];
  const float* bias = (const float*)d_in[2];
  float* out = (float*)d_out;

  char* ws = (char*)d_ws;
  size_t off = 0;
  unsigned char*  uh = (unsigned char*)(ws + off);  off += (size_t)B_ * I_ * K_;      // 134 MB u8
  unsigned short* sc = (unsigned short*)(ws + off); off += (size_t)B_ * I_ * N_ * 2;  // 16.8 MB f16 scales
  float* s0 = (float*)(ws + off); off += (size_t)B_ * K_ * 4;
  float* s1 = (float*)(ws + off); off += (size_t)B_ * K_ * 4;
  float* s2 = (float*)(ws + off); off += (size_t)B_ * K_ * 4;

  if (ws_size < off)
    fprintf(stderr, "ClassCapsule: ws_size=%zu < needed=%zu — expect corruption\n", ws_size, off);

  (void)hipMemsetAsync(s0, 0, (size_t)3 * B_ * K_ * 4, stream);  // s0,s1,s2 contiguous

  project_k<<<dim3(I_ * 2), dim3(256), 0, stream>>>(x, W, uh, sc);

  route_k<0><<<dim3(1024), dim3(256), 0, stream>>>(uh, sc, nullptr, nullptr, bias, s0);
  route_k<1><<<dim3(1024), dim3(256), 0, stream>>>(uh, sc, s0, nullptr, bias, s1);
  route_k<2><<<dim3(1024), dim3(256), 0, stream>>>(uh, sc, s0, s1, bias, s2);
  squash_k<<<dim3(B_), dim3(256), 0, stream>>>(s2, bias, out);
}